// Round 1
// baseline (168.145 us; speedup 1.0000x reference)
//
#include <hip/hip_runtime.h>
#include <math.h>

#define BB 16
#define NN 4096            // N == M == 4096
#define KK 128
#define W_POINT  1.0f
#define W_COEFF  0.5f
#define W_AFFINE 0.5f

// Compute R = Rx @ Ry @ Rz (row-major, applied as out[e] = sum_d in[d]*R[d*3+e]),
// plus scale/trans, from the 9-float affine vector.
__device__ inline void compute_affine(const float* __restrict__ aff,
                                      float R[9], float sc[3], float tr[3]) {
    float ax = aff[0], ay = aff[1], az = aff[2];
    tr[0] = aff[3]; tr[1] = aff[4]; tr[2] = aff[5];
    sc[0] = aff[6]; sc[1] = aff[7]; sc[2] = aff[8];
    float cx = cosf(ax), sx = sinf(ax);
    float cy = cosf(ay), sy = sinf(ay);
    float cz = cosf(az), sz = sinf(az);
    // M1 = Ry @ Rz = [cy*cz, -cy*sz, sy; sz, cz, 0; -sy*cz, sy*sz, cy]
    // R = Rx @ M1:
    R[0] = cy * cz;                 R[1] = -cy * sz;                R[2] = sy;
    R[3] = cx * sz + sx * sy * cz;  R[4] = cx * cz - sx * sy * sz;  R[5] = -sx * cy;
    R[6] = sx * sz - cx * sy * cz;  R[7] = sx * cz + cx * sy * sz;  R[8] = cx * cy;
}

__device__ inline void apply_affine(const float R[9], const float sc[3], const float tr[3],
                                    float x, float y, float z,
                                    float& ox, float& oy, float& oz) {
    ox = fmaf(fmaf(x, R[0], fmaf(y, R[3], z * R[6])), sc[0], tr[0]);
    oy = fmaf(fmaf(x, R[1], fmaf(y, R[4], z * R[7])), sc[1], tr[1]);
    oz = fmaf(fmaf(x, R[2], fmaf(y, R[5], z * R[8])), sc[2], tr[2]);
}

// grid: (BB*16, 2). blockIdx.y = direction.
//   dir 0: query = pred points, reference = transformed targ points
//   dir 1: query = transformed targ points, reference = pred points
// Each block: stage all 4096 reference points of batch b into LDS as
// (x, y, z, |t|^2), then each of 256 threads scans them for its one query.
__global__ __launch_bounds__(256) void chamfer_kernel(
        const float* __restrict__ pred_shape,
        const float* __restrict__ targ_shape,
        const float* __restrict__ targ_affine,
        float* __restrict__ accum) {
    __shared__ float4 lds[NN];   // 64 KiB exactly

    const int b     = blockIdx.x >> 4;
    const int chunk = blockIdx.x & 15;
    const int dir   = blockIdx.y;
    const int tid   = threadIdx.x;

    float R[9], sc[3], tr[3];
    compute_affine(targ_affine + b * 9, R, sc, tr);

    // ---- stage reference points into LDS ----
    if (dir == 0) {
        const float* ts = targ_shape + (size_t)b * NN * 3;
        for (int i = tid; i < NN; i += 256) {
            float x = ts[i * 3 + 0], y = ts[i * 3 + 1], z = ts[i * 3 + 2];
            float mx, my, mz;
            apply_affine(R, sc, tr, x, y, z, mx, my, mz);
            lds[i] = make_float4(mx, my, mz, fmaf(mx, mx, fmaf(my, my, mz * mz)));
        }
    } else {
        const float* ps = pred_shape + (size_t)b * NN * 3;
        for (int i = tid; i < NN; i += 256) {
            float x = ps[i * 3 + 0], y = ps[i * 3 + 1], z = ps[i * 3 + 2];
            lds[i] = make_float4(x, y, z, fmaf(x, x, fmaf(y, y, z * z)));
        }
    }
    __syncthreads();

    // ---- load my query point ----
    const int qi = chunk * 256 + tid;
    float qx, qy, qz;
    if (dir == 0) {
        const float* ps = pred_shape + ((size_t)b * NN + qi) * 3;
        qx = ps[0]; qy = ps[1]; qz = ps[2];
    } else {
        const float* ts = targ_shape + ((size_t)b * NN + qi) * 3;
        apply_affine(R, sc, tr, ts[0], ts[1], ts[2], qx, qy, qz);
    }
    const float q2 = fmaf(qx, qx, fmaf(qy, qy, qz * qz));
    const float ax = -2.0f * qx, ay = -2.0f * qy, az = -2.0f * qz;

    // ---- scan: min over reference of (|t|^2 - 2 q.t)  (q2 added at end) ----
    float mv[8];
    #pragma unroll
    for (int u = 0; u < 8; ++u) mv[u] = 1e30f;
    for (int j = 0; j < NN; j += 8) {
        #pragma unroll
        for (int u = 0; u < 8; ++u) {
            float4 t = lds[j + u];
            float v = fmaf(ax, t.x, fmaf(ay, t.y, fmaf(az, t.z, t.w)));
            mv[u] = fminf(mv[u], v);
        }
    }
    float mn = fminf(fminf(fminf(mv[0], mv[1]), fminf(mv[2], mv[3])),
                     fminf(fminf(mv[4], mv[5]), fminf(mv[6], mv[7])));
    float d = fmaxf(q2 + mn, 0.0f);   // clamp commutes with min

    // ---- reduce: wave shuffle, then one atomic per wave ----
    #pragma unroll
    for (int off = 32; off > 0; off >>= 1) d += __shfl_down(d, off);
    if ((tid & 63) == 0) atomicAdd(accum, d);
}

__global__ __launch_bounds__(256) void finalize_kernel(
        const float* __restrict__ pred_w,  const float* __restrict__ targ_w,
        const float* __restrict__ pred_aff, const float* __restrict__ targ_aff,
        const float* __restrict__ accum,   float* __restrict__ out) {
    const int tid = threadIdx.x;
    float cs = 0.0f;
    for (int i = tid; i < BB * KK; i += 256) {
        float dd = pred_w[i] - targ_w[i];
        cs = fmaf(dd, dd, cs);
    }
    float as = 0.0f;
    for (int i = tid; i < BB * 9; i += 256) {
        float dd = pred_aff[i] - targ_aff[i];
        as = fmaf(dd, dd, as);
    }
    #pragma unroll
    for (int off = 32; off > 0; off >>= 1) {
        cs += __shfl_down(cs, off);
        as += __shfl_down(as, off);
    }
    __shared__ float scs[4], sas[4];
    const int wid = tid >> 6;
    if ((tid & 63) == 0) { scs[wid] = cs; sas[wid] = as; }
    __syncthreads();
    if (tid == 0) {
        float coeff  = (scs[0] + scs[1] + scs[2] + scs[3]) / (float)(BB * KK);
        float affine = (sas[0] + sas[1] + sas[2] + sas[3]) / (float)(BB * 9);
        float point  = accum[0] / (float)(BB * NN);   // both directions share denom
        out[0] = W_POINT * point + W_COEFF * coeff + W_AFFINE * affine;
        out[1] = point;
        out[2] = coeff;
        out[3] = affine;
    }
}

extern "C" void kernel_launch(void* const* d_in, const int* in_sizes, int n_in,
                              void* d_out, int out_size, void* d_ws, size_t ws_size,
                              hipStream_t stream) {
    const float* pred_shape = (const float*)d_in[0];
    const float* pred_w     = (const float*)d_in[1];
    const float* pred_aff   = (const float*)d_in[2];
    const float* targ_shape = (const float*)d_in[3];
    const float* targ_w     = (const float*)d_in[4];
    const float* targ_aff   = (const float*)d_in[5];
    float* out   = (float*)d_out;
    float* accum = (float*)d_ws;

    hipMemsetAsync(accum, 0, sizeof(float), stream);
    chamfer_kernel<<<dim3(BB * 16, 2), 256, 0, stream>>>(pred_shape, targ_shape,
                                                         targ_aff, accum);
    finalize_kernel<<<1, 256, 0, stream>>>(pred_w, targ_w, pred_aff, targ_aff,
                                           accum, out);
}

// Round 2
// 123.096 us; speedup vs baseline: 1.3660x; 1.3660x over previous
//
#include <hip/hip_runtime.h>
#include <math.h>

#define BB 16
#define NN 4096            // N == M == 4096
#define KK 128
#define NTILE 8            // reference tiles per batch
#define TS (NN / NTILE)    // 512 refs per tile -> 8 KiB LDS
#define NCHUNK 4           // query chunks per (b, dir)
#define QPT 4              // queries per thread
#define TPB 256
#define W_POINT  1.0f
#define W_COEFF  0.5f
#define W_AFFINE 0.5f

__device__ inline void compute_affine(const float* __restrict__ aff,
                                      float R[9], float sc[3], float tr[3]) {
    float ax = aff[0], ay = aff[1], az = aff[2];
    tr[0] = aff[3]; tr[1] = aff[4]; tr[2] = aff[5];
    sc[0] = aff[6]; sc[1] = aff[7]; sc[2] = aff[8];
    float cx = cosf(ax), sx = sinf(ax);
    float cy = cosf(ay), sy = sinf(ay);
    float cz = cosf(az), sz = sinf(az);
    R[0] = cy * cz;                 R[1] = -cy * sz;                R[2] = sy;
    R[3] = cx * sz + sx * sy * cz;  R[4] = cx * cz - sx * sy * sz;  R[5] = -sx * cy;
    R[6] = sx * sz - cx * sy * cz;  R[7] = sx * cz + cx * sy * sz;  R[8] = cx * cy;
}

__device__ inline void apply_affine(const float R[9], const float sc[3], const float tr[3],
                                    float x, float y, float z,
                                    float& ox, float& oy, float& oz) {
    ox = fmaf(fmaf(x, R[0], fmaf(y, R[3], z * R[6])), sc[0], tr[0]);
    oy = fmaf(fmaf(x, R[1], fmaf(y, R[4], z * R[7])), sc[1], tr[1]);
    oz = fmaf(fmaf(x, R[2], fmaf(y, R[5], z * R[8])), sc[2], tr[2]);
}

// grid.x = BB * NCHUNK * NTILE (b-major, then chunk, then tile), grid.y = dir.
// Each block: stage its 512-ref tile (transformed for dir 0) into LDS, then
// each thread scans the tile for its 4 query points; partial mins combined
// across tile-blocks via atomicMin on float-as-uint (all values >= 0).
__global__ __launch_bounds__(TPB, 4) void chamfer_kernel(
        const float* __restrict__ pred_shape,
        const float* __restrict__ targ_shape,
        const float* __restrict__ targ_affine,
        unsigned int* __restrict__ pmin) {
    __shared__ float4 lds[TS];   // 8 KiB

    const int bx    = blockIdx.x;
    const int tile  = bx & (NTILE - 1);
    const int chunk = (bx >> 3) & (NCHUNK - 1);
    const int b     = bx >> 5;
    const int dir   = blockIdx.y;
    const int tid   = threadIdx.x;

    float R[9], sc[3], tr[3];
    compute_affine(targ_affine + b * 9, R, sc, tr);

    // ---- stage this block's reference tile ----
    const int rbase = tile * TS;
    if (dir == 0) {
        const float* ts = targ_shape + ((size_t)b * NN + rbase) * 3;
        for (int i = tid; i < TS; i += TPB) {
            float x = ts[i * 3 + 0], y = ts[i * 3 + 1], z = ts[i * 3 + 2];
            float mx, my, mz;
            apply_affine(R, sc, tr, x, y, z, mx, my, mz);
            lds[i] = make_float4(mx, my, mz, fmaf(mx, mx, fmaf(my, my, mz * mz)));
        }
    } else {
        const float* ps = pred_shape + ((size_t)b * NN + rbase) * 3;
        for (int i = tid; i < TS; i += TPB) {
            float x = ps[i * 3 + 0], y = ps[i * 3 + 1], z = ps[i * 3 + 2];
            lds[i] = make_float4(x, y, z, fmaf(x, x, fmaf(y, y, z * z)));
        }
    }
    __syncthreads();

    // ---- load 4 query points per thread ----
    const int qbase = chunk * (TPB * QPT);
    float ax[QPT], ay[QPT], az[QPT], q2[QPT], mn[QPT];
    #pragma unroll
    for (int k = 0; k < QPT; ++k) {
        const int qi = qbase + k * TPB + tid;
        float x, y, z;
        if (dir == 0) {
            const float* p = pred_shape + ((size_t)b * NN + qi) * 3;
            x = p[0]; y = p[1]; z = p[2];
        } else {
            const float* t = targ_shape + ((size_t)b * NN + qi) * 3;
            apply_affine(R, sc, tr, t[0], t[1], t[2], x, y, z);
        }
        q2[k] = fmaf(x, x, fmaf(y, y, z * z));
        ax[k] = -2.0f * x; ay[k] = -2.0f * y; az[k] = -2.0f * z;
        mn[k] = 1e30f;
    }

    // ---- scan tile: per ref, v = |t|^2 - 2 q.t; track min per query ----
    for (int j = 0; j < TS; j += 4) {
        float4 t0 = lds[j + 0], t1 = lds[j + 1], t2 = lds[j + 2], t3 = lds[j + 3];
        #pragma unroll
        for (int k = 0; k < QPT; ++k) {
            float v0 = fmaf(ax[k], t0.x, fmaf(ay[k], t0.y, fmaf(az[k], t0.z, t0.w)));
            float v1 = fmaf(ax[k], t1.x, fmaf(ay[k], t1.y, fmaf(az[k], t1.z, t1.w)));
            float v2 = fmaf(ax[k], t2.x, fmaf(ay[k], t2.y, fmaf(az[k], t2.z, t2.w)));
            float v3 = fmaf(ax[k], t3.x, fmaf(ay[k], t3.y, fmaf(az[k], t3.z, t3.w)));
            mn[k] = fminf(mn[k], fminf(fminf(v0, v1), fminf(v2, v3)));
        }
    }

    // ---- clamp and combine across tile-blocks ----
    #pragma unroll
    for (int k = 0; k < QPT; ++k) {
        const int qi = qbase + k * TPB + tid;
        float d = fmaxf(q2[k] + mn[k], 0.0f);           // >= 0 -> uint order == float order
        atomicMin(&pmin[((size_t)dir * BB + b) * NN + qi], __float_as_uint(d));
    }
}

__global__ __launch_bounds__(1024) void finalize_kernel(
        const unsigned int* __restrict__ pmin,
        const float* __restrict__ pred_w,  const float* __restrict__ targ_w,
        const float* __restrict__ pred_aff, const float* __restrict__ targ_aff,
        float* __restrict__ out) {
    const int tid = threadIdx.x;

    float ps = 0.0f;
    const int total4 = (2 * BB * NN) / 4;     // 32768 uint4's
    const uint4* pm4 = (const uint4*)pmin;
    for (int i = tid; i < total4; i += 1024) {
        uint4 u = pm4[i];
        ps += __uint_as_float(u.x) + __uint_as_float(u.y)
            + __uint_as_float(u.z) + __uint_as_float(u.w);
    }
    float cs = 0.0f;
    for (int i = tid; i < BB * KK; i += 1024) {
        float d = pred_w[i] - targ_w[i];
        cs = fmaf(d, d, cs);
    }
    float as = 0.0f;
    if (tid < BB * 9) {
        float d = pred_aff[tid] - targ_aff[tid];
        as = d * d;
    }

    #pragma unroll
    for (int off = 32; off > 0; off >>= 1) {
        ps += __shfl_down(ps, off);
        cs += __shfl_down(cs, off);
        as += __shfl_down(as, off);
    }
    __shared__ float sps[16], scs[16], sas[16];
    const int wid = tid >> 6;
    if ((tid & 63) == 0) { sps[wid] = ps; scs[wid] = cs; sas[wid] = as; }
    __syncthreads();
    if (tid == 0) {
        float p = 0.0f, c = 0.0f, a = 0.0f;
        #pragma unroll
        for (int w = 0; w < 16; ++w) { p += sps[w]; c += scs[w]; a += sas[w]; }
        float point  = p / (float)(BB * NN);   // both directions share denom
        float coeff  = c / (float)(BB * KK);
        float affine = a / (float)(BB * 9);
        out[0] = W_POINT * point + W_COEFF * coeff + W_AFFINE * affine;
        out[1] = point;
        out[2] = coeff;
        out[3] = affine;
    }
}

extern "C" void kernel_launch(void* const* d_in, const int* in_sizes, int n_in,
                              void* d_out, int out_size, void* d_ws, size_t ws_size,
                              hipStream_t stream) {
    const float* pred_shape = (const float*)d_in[0];
    const float* pred_w     = (const float*)d_in[1];
    const float* pred_aff   = (const float*)d_in[2];
    const float* targ_shape = (const float*)d_in[3];
    const float* targ_w     = (const float*)d_in[4];
    const float* targ_aff   = (const float*)d_in[5];
    float* out = (float*)d_out;
    unsigned int* pmin = (unsigned int*)d_ws;   // 2*BB*NN*4 = 512 KiB

    // init partial mins to a huge positive float (0x7f7f7f7f = 3.39e38)
    hipMemsetAsync(pmin, 0x7f, (size_t)2 * BB * NN * sizeof(unsigned int), stream);

    chamfer_kernel<<<dim3(BB * NCHUNK * NTILE, 2), TPB, 0, stream>>>(
        pred_shape, targ_shape, targ_aff, pmin);
    finalize_kernel<<<1, 1024, 0, stream>>>(pmin, pred_w, targ_w,
                                            pred_aff, targ_aff, out);
}

// Round 3
// 112.815 us; speedup vs baseline: 1.4904x; 1.0911x over previous
//
#include <hip/hip_runtime.h>
#include <math.h>

#define BB 16
#define NN 4096            // N == M == 4096
#define KK 128
#define NTILE 16           // reference tiles per batch
#define TS (NN / NTILE)    // 256 refs per tile -> 4 KiB LDS
#define NCHUNK 2           // query chunks per (b, dir)
#define QPT 8              // queries per thread
#define TPB 256
#define W_POINT  1.0f
#define W_COEFF  0.5f
#define W_AFFINE 0.5f

__device__ inline void compute_affine(const float* __restrict__ aff,
                                      float R[9], float sc[3], float tr[3]) {
    float ax = aff[0], ay = aff[1], az = aff[2];
    tr[0] = aff[3]; tr[1] = aff[4]; tr[2] = aff[5];
    sc[0] = aff[6]; sc[1] = aff[7]; sc[2] = aff[8];
    float cx = cosf(ax), sx = sinf(ax);
    float cy = cosf(ay), sy = sinf(ay);
    float cz = cosf(az), sz = sinf(az);
    R[0] = cy * cz;                 R[1] = -cy * sz;                R[2] = sy;
    R[3] = cx * sz + sx * sy * cz;  R[4] = cx * cz - sx * sy * sz;  R[5] = -sx * cy;
    R[6] = sx * sz - cx * sy * cz;  R[7] = sx * cz + cx * sy * sz;  R[8] = cx * cy;
}

__device__ inline void apply_affine(const float R[9], const float sc[3], const float tr[3],
                                    float x, float y, float z,
                                    float& ox, float& oy, float& oz) {
    ox = fmaf(fmaf(x, R[0], fmaf(y, R[3], z * R[6])), sc[0], tr[0]);
    oy = fmaf(fmaf(x, R[1], fmaf(y, R[4], z * R[7])), sc[1], tr[1]);
    oz = fmaf(fmaf(x, R[2], fmaf(y, R[5], z * R[8])), sc[2], tr[2]);
}

// grid.x = BB * NCHUNK * NTILE (b-major, then chunk, then tile), grid.y = dir.
// Each block: stage its 256-ref tile (transformed for dir 0) into LDS, then
// each thread scans the tile for its 8 query points; partial mins combined
// across tile-blocks via atomicMin on float-as-uint (all values >= 0).
__global__ __launch_bounds__(TPB, 4) void chamfer_kernel(
        const float* __restrict__ pred_shape,
        const float* __restrict__ targ_shape,
        const float* __restrict__ targ_affine,
        unsigned int* __restrict__ pmin) {
    __shared__ float4 lds[TS];   // 4 KiB

    const int bx    = blockIdx.x;
    const int tile  = bx & (NTILE - 1);
    const int chunk = (bx >> 4) & (NCHUNK - 1);
    const int b     = bx >> 5;
    const int dir   = blockIdx.y;
    const int tid   = threadIdx.x;

    float R[9], sc[3], tr[3];
    compute_affine(targ_affine + b * 9, R, sc, tr);

    // ---- stage this block's reference tile (one ref per thread) ----
    {
        const int rbase = tile * TS;
        if (dir == 0) {
            const float* ts = targ_shape + ((size_t)b * NN + rbase + tid) * 3;
            float x = ts[0], y = ts[1], z = ts[2];
            float mx, my, mz;
            apply_affine(R, sc, tr, x, y, z, mx, my, mz);
            lds[tid] = make_float4(mx, my, mz, fmaf(mx, mx, fmaf(my, my, mz * mz)));
        } else {
            const float* ps = pred_shape + ((size_t)b * NN + rbase + tid) * 3;
            float x = ps[0], y = ps[1], z = ps[2];
            lds[tid] = make_float4(x, y, z, fmaf(x, x, fmaf(y, y, z * z)));
        }
    }
    __syncthreads();

    // ---- load 8 query points per thread ----
    const int qbase = chunk * (TPB * QPT);
    float ax[QPT], ay[QPT], az[QPT], q2[QPT], mn[QPT];
    #pragma unroll
    for (int k = 0; k < QPT; ++k) {
        const int qi = qbase + k * TPB + tid;
        float x, y, z;
        if (dir == 0) {
            const float* p = pred_shape + ((size_t)b * NN + qi) * 3;
            x = p[0]; y = p[1]; z = p[2];
        } else {
            const float* t = targ_shape + ((size_t)b * NN + qi) * 3;
            apply_affine(R, sc, tr, t[0], t[1], t[2], x, y, z);
        }
        q2[k] = fmaf(x, x, fmaf(y, y, z * z));
        ax[k] = -2.0f * x; ay[k] = -2.0f * y; az[k] = -2.0f * z;
        mn[k] = 1e30f;
    }

    // ---- scan tile: per ref, v = |t|^2 - 2 q.t; track min per query ----
    for (int j = 0; j < TS; j += 4) {
        float4 t0 = lds[j + 0], t1 = lds[j + 1], t2 = lds[j + 2], t3 = lds[j + 3];
        #pragma unroll
        for (int k = 0; k < QPT; ++k) {
            float v0 = fmaf(ax[k], t0.x, fmaf(ay[k], t0.y, fmaf(az[k], t0.z, t0.w)));
            float v1 = fmaf(ax[k], t1.x, fmaf(ay[k], t1.y, fmaf(az[k], t1.z, t1.w)));
            float v2 = fmaf(ax[k], t2.x, fmaf(ay[k], t2.y, fmaf(az[k], t2.z, t2.w)));
            float v3 = fmaf(ax[k], t3.x, fmaf(ay[k], t3.y, fmaf(az[k], t3.z, t3.w)));
            mn[k] = fminf(mn[k], fminf(fminf(v0, v1), fminf(v2, v3)));
        }
    }

    // ---- clamp and combine across tile-blocks ----
    #pragma unroll
    for (int k = 0; k < QPT; ++k) {
        const int qi = qbase + k * TPB + tid;
        float d = fmaxf(q2[k] + mn[k], 0.0f);           // >= 0 -> uint order == float order
        atomicMin(&pmin[((size_t)dir * BB + b) * NN + qi], __float_as_uint(d));
    }
}

// 32 blocks: block i sums pmin[i*4096 .. +4096) -> partials[i] (plain store).
__global__ __launch_bounds__(TPB) void reduce_pmin(
        const unsigned int* __restrict__ pmin,
        float* __restrict__ partials) {
    const int tid = threadIdx.x;
    const uint4* pm4 = (const uint4*)(pmin + (size_t)blockIdx.x * 4096);
    float ps = 0.0f;
    #pragma unroll
    for (int r = 0; r < 4; ++r) {                 // 1024 uint4 per block
        uint4 u = pm4[r * TPB + tid];
        ps += __uint_as_float(u.x) + __uint_as_float(u.y)
            + __uint_as_float(u.z) + __uint_as_float(u.w);
    }
    #pragma unroll
    for (int off = 32; off > 0; off >>= 1) ps += __shfl_down(ps, off);
    __shared__ float sps[4];
    const int wid = tid >> 6;
    if ((tid & 63) == 0) sps[wid] = ps;
    __syncthreads();
    if (tid == 0) partials[blockIdx.x] = sps[0] + sps[1] + sps[2] + sps[3];
}

__global__ __launch_bounds__(TPB) void final_combine(
        const float* __restrict__ partials,
        const float* __restrict__ pred_w,  const float* __restrict__ targ_w,
        const float* __restrict__ pred_aff, const float* __restrict__ targ_aff,
        float* __restrict__ out) {
    const int tid = threadIdx.x;
    float ps = (tid < 32) ? partials[tid] : 0.0f;
    float cs = 0.0f;
    #pragma unroll
    for (int r = 0; r < (BB * KK) / TPB; ++r) {   // 2048 floats
        float d = pred_w[r * TPB + tid] - targ_w[r * TPB + tid];
        cs = fmaf(d, d, cs);
    }
    float as = 0.0f;
    if (tid < BB * 9) {
        float d = pred_aff[tid] - targ_aff[tid];
        as = d * d;
    }
    #pragma unroll
    for (int off = 32; off > 0; off >>= 1) {
        ps += __shfl_down(ps, off);
        cs += __shfl_down(cs, off);
        as += __shfl_down(as, off);
    }
    __shared__ float sps[4], scs[4], sas[4];
    const int wid = tid >> 6;
    if ((tid & 63) == 0) { sps[wid] = ps; scs[wid] = cs; sas[wid] = as; }
    __syncthreads();
    if (tid == 0) {
        float p = sps[0] + sps[1] + sps[2] + sps[3];
        float c = scs[0] + scs[1] + scs[2] + scs[3];
        float a = sas[0] + sas[1] + sas[2] + sas[3];
        float point  = p / (float)(BB * NN);   // both directions share denom
        float coeff  = c / (float)(BB * KK);
        float affine = a / (float)(BB * 9);
        out[0] = W_POINT * point + W_COEFF * coeff + W_AFFINE * affine;
        out[1] = point;
        out[2] = coeff;
        out[3] = affine;
    }
}

extern "C" void kernel_launch(void* const* d_in, const int* in_sizes, int n_in,
                              void* d_out, int out_size, void* d_ws, size_t ws_size,
                              hipStream_t stream) {
    const float* pred_shape = (const float*)d_in[0];
    const float* pred_w     = (const float*)d_in[1];
    const float* pred_aff   = (const float*)d_in[2];
    const float* targ_shape = (const float*)d_in[3];
    const float* targ_w     = (const float*)d_in[4];
    const float* targ_aff   = (const float*)d_in[5];
    float* out = (float*)d_out;
    unsigned int* pmin = (unsigned int*)d_ws;            // 2*BB*NN = 131072 words (512 KiB)
    float* partials = (float*)(pmin + 2 * BB * NN);      // 32 floats

    // init partial mins to a huge positive float (0x7f7f7f7f = 3.39e38)
    hipMemsetAsync(pmin, 0x7f, (size_t)2 * BB * NN * sizeof(unsigned int), stream);

    chamfer_kernel<<<dim3(BB * NCHUNK * NTILE, 2), TPB, 0, stream>>>(
        pred_shape, targ_shape, targ_aff, pmin);
    reduce_pmin<<<32, TPB, 0, stream>>>(pmin, partials);
    final_combine<<<1, TPB, 0, stream>>>(partials, pred_w, targ_w,
                                         pred_aff, targ_aff, out);
}

// Round 4
// 101.874 us; speedup vs baseline: 1.6505x; 1.1074x over previous
//
#include <hip/hip_runtime.h>
#include <math.h>

#define BB 16
#define NN 4096            // N == M == 4096
#define KK 128
#define RT 2048            // rows per block  (8 per thread)
#define CT 128             // cols per block  (2 rotation groups of 64)
#define RPT 8              // rows per thread
#define TPB 256
#define NRTILE (NN / RT)   // 2
#define NCTILE (NN / CT)   // 32
#define W_POINT  1.0f
#define W_COEFF  0.5f
#define W_AFFINE 0.5f

__device__ inline float min3f(float a, float b, float c) {
    float r;
    asm("v_min3_f32 %0, %1, %2, %3" : "=v"(r) : "v"(a), "v"(b), "v"(c));
    return r;
}

__device__ inline void compute_affine(const float* __restrict__ aff,
                                      float R[9], float sc[3], float tr[3]) {
    float ax = aff[0], ay = aff[1], az = aff[2];
    tr[0] = aff[3]; tr[1] = aff[4]; tr[2] = aff[5];
    sc[0] = aff[6]; sc[1] = aff[7]; sc[2] = aff[8];
    float cx = cosf(ax), sx = sinf(ax);
    float cy = cosf(ay), sy = sinf(ay);
    float cz = cosf(az), sz = sinf(az);
    R[0] = cy * cz;                 R[1] = -cy * sz;                R[2] = sy;
    R[3] = cx * sz + sx * sy * cz;  R[4] = cx * cz - sx * sy * sz;  R[5] = -sx * cy;
    R[6] = sx * sz - cx * sy * cz;  R[7] = sx * cz + cx * sy * sz;  R[8] = cx * cy;
}

__device__ inline void apply_affine(const float R[9], const float sc[3], const float tr[3],
                                    float x, float y, float z,
                                    float& ox, float& oy, float& oz) {
    ox = fmaf(fmaf(x, R[0], fmaf(y, R[3], z * R[6])), sc[0], tr[0]);
    oy = fmaf(fmaf(x, R[1], fmaf(y, R[4], z * R[7])), sc[1], tr[1]);
    oz = fmaf(fmaf(x, R[2], fmaf(y, R[5], z * R[8])), sc[2], tr[2]);
}

// One-pass Chamfer: each block owns a 2048-row x 128-col tile of the d2
// matrix for one batch. Rows (pred) live in registers (8/thread); cols
// (transformed targ, with |t|^2) live in LDS. Each pair is evaluated ONCE;
// row-mins accumulate thread-locally, col-mins accumulate in a register that
// rotates across lanes (lane l at iter i handles col (l+i)&63) so no
// cross-lane reduction is ever needed. Global merge via atomicMin on
// float-as-uint (values clamped >= 0 first).
__global__ __launch_bounds__(TPB, 4) void chamfer_kernel(
        const float* __restrict__ pred_shape,
        const float* __restrict__ targ_shape,
        const float* __restrict__ targ_affine,
        unsigned int* __restrict__ pmin) {
    __shared__ float4 ldsc[CT];          // 2 KiB

    const int bx    = blockIdx.x;
    const int ctile = bx & (NCTILE - 1);
    const int rtile = (bx >> 5) & (NRTILE - 1);
    const int b     = bx >> 6;
    const int tid   = threadIdx.x;
    const int lane  = tid & 63;

    float R[9], sc[3], tr[3];
    compute_affine(targ_affine + b * 9, R, sc, tr);

    // ---- stage 128 transformed target cols ----
    if (tid < CT) {
        const float* t = targ_shape + ((size_t)b * NN + ctile * CT + tid) * 3;
        float mx, my, mz;
        apply_affine(R, sc, tr, t[0], t[1], t[2], mx, my, mz);
        ldsc[tid] = make_float4(mx, my, mz, fmaf(mx, mx, fmaf(my, my, mz * mz)));
    }

    // ---- load 8 pred rows per thread ----
    const int rowbase = rtile * RT;
    float ax[RPT], ay[RPT], az[RPT], q2[RPT], rmin[RPT];
    #pragma unroll
    for (int k = 0; k < RPT; ++k) {
        const float* p = pred_shape + ((size_t)b * NN + rowbase + k * TPB + tid) * 3;
        float x = p[0], y = p[1], z = p[2];
        q2[k] = fmaf(x, x, fmaf(y, y, z * z));
        ax[k] = -2.0f * x; ay[k] = -2.0f * y; az[k] = -2.0f * z;
        rmin[k] = 1e30f;
    }
    __syncthreads();

    // ---- rotating scan: iter i, lane l handles cols (l+i)&63 and +64 ----
    float cr0 = 1e30f, cr1 = 1e30f;      // rotating col-min accumulators
    const int rot = ((lane + 1) & 63) << 2;
    for (int i = 0; i < 64; ++i) {
        const int idx = (lane + i) & 63;
        float4 t0 = ldsc[idx];
        float4 t1 = ldsc[idx + 64];
        float da[RPT], db[RPT];
        #pragma unroll
        for (int k = 0; k < RPT; ++k) {
            float s0 = q2[k] + t0.w;
            float s1 = q2[k] + t1.w;
            float e0 = fmaf(ax[k], t0.x, fmaf(ay[k], t0.y, fmaf(az[k], t0.z, s0)));
            float e1 = fmaf(ax[k], t1.x, fmaf(ay[k], t1.y, fmaf(az[k], t1.z, s1)));
            rmin[k] = min3f(rmin[k], e0, e1);
            da[k] = e0; db[k] = e1;
        }
        // col-min over this lane's 8 rows, merged into rotating accumulator
        float a0 = min3f(da[0], da[1], da[2]);
        float b0 = min3f(da[3], da[4], da[5]);
        float c0 = min3f(da[6], da[7], cr0);
        cr0 = min3f(a0, b0, c0);
        float a1 = min3f(db[0], db[1], db[2]);
        float b1 = min3f(db[3], db[4], db[5]);
        float c1 = min3f(db[6], db[7], cr1);
        cr1 = min3f(a1, b1, c1);
        // rotate accumulators down one lane: new[l] = old[(l+1)&63]
        cr0 = __int_as_float(__builtin_amdgcn_ds_bpermute(rot, __float_as_int(cr0)));
        cr1 = __int_as_float(__builtin_amdgcn_ds_bpermute(rot, __float_as_int(cr1)));
    }
    // after 64 iters + 64 rotates, lane l holds col (ctile*CT + l) / (+64)

    // ---- merge row-mins ----
    #pragma unroll
    for (int k = 0; k < RPT; ++k) {
        float d = fmaxf(rmin[k], 0.0f);   // clamp commutes with min
        atomicMin(&pmin[(size_t)b * NN + rowbase + k * TPB + tid],
                  __float_as_uint(d));
    }
    // ---- merge col-mins (one per lane per group, per wave) ----
    {
        float d0 = fmaxf(cr0, 0.0f);
        atomicMin(&pmin[(size_t)(BB + b) * NN + ctile * CT + lane],
                  __float_as_uint(d0));
        float d1 = fmaxf(cr1, 0.0f);
        atomicMin(&pmin[(size_t)(BB + b) * NN + ctile * CT + 64 + lane],
                  __float_as_uint(d1));
    }
}

// 32 blocks: block i sums pmin[i*4096 .. +4096) -> partials[i] (plain store).
__global__ __launch_bounds__(TPB) void reduce_pmin(
        const unsigned int* __restrict__ pmin,
        float* __restrict__ partials) {
    const int tid = threadIdx.x;
    const uint4* pm4 = (const uint4*)(pmin + (size_t)blockIdx.x * 4096);
    float ps = 0.0f;
    #pragma unroll
    for (int r = 0; r < 4; ++r) {                 // 1024 uint4 per block
        uint4 u = pm4[r * TPB + tid];
        ps += __uint_as_float(u.x) + __uint_as_float(u.y)
            + __uint_as_float(u.z) + __uint_as_float(u.w);
    }
    #pragma unroll
    for (int off = 32; off > 0; off >>= 1) ps += __shfl_down(ps, off);
    __shared__ float sps[4];
    const int wid = tid >> 6;
    if ((tid & 63) == 0) sps[wid] = ps;
    __syncthreads();
    if (tid == 0) partials[blockIdx.x] = sps[0] + sps[1] + sps[2] + sps[3];
}

__global__ __launch_bounds__(TPB) void final_combine(
        const float* __restrict__ partials,
        const float* __restrict__ pred_w,  const float* __restrict__ targ_w,
        const float* __restrict__ pred_aff, const float* __restrict__ targ_aff,
        float* __restrict__ out) {
    const int tid = threadIdx.x;
    float ps = (tid < 32) ? partials[tid] : 0.0f;
    float cs = 0.0f;
    #pragma unroll
    for (int r = 0; r < (BB * KK) / TPB; ++r) {   // 2048 floats
        float d = pred_w[r * TPB + tid] - targ_w[r * TPB + tid];
        cs = fmaf(d, d, cs);
    }
    float as = 0.0f;
    if (tid < BB * 9) {
        float d = pred_aff[tid] - targ_aff[tid];
        as = d * d;
    }
    #pragma unroll
    for (int off = 32; off > 0; off >>= 1) {
        ps += __shfl_down(ps, off);
        cs += __shfl_down(cs, off);
        as += __shfl_down(as, off);
    }
    __shared__ float sps[4], scs[4], sas[4];
    const int wid = tid >> 6;
    if ((tid & 63) == 0) { sps[wid] = ps; scs[wid] = cs; sas[wid] = as; }
    __syncthreads();
    if (tid == 0) {
        float p = sps[0] + sps[1] + sps[2] + sps[3];
        float c = scs[0] + scs[1] + scs[2] + scs[3];
        float a = sas[0] + sas[1] + sas[2] + sas[3];
        float point  = p / (float)(BB * NN);   // row-min and col-min share denom
        float coeff  = c / (float)(BB * KK);
        float affine = a / (float)(BB * 9);
        out[0] = W_POINT * point + W_COEFF * coeff + W_AFFINE * affine;
        out[1] = point;
        out[2] = coeff;
        out[3] = affine;
    }
}

extern "C" void kernel_launch(void* const* d_in, const int* in_sizes, int n_in,
                              void* d_out, int out_size, void* d_ws, size_t ws_size,
                              hipStream_t stream) {
    const float* pred_shape = (const float*)d_in[0];
    const float* pred_w     = (const float*)d_in[1];
    const float* pred_aff   = (const float*)d_in[2];
    const float* targ_shape = (const float*)d_in[3];
    const float* targ_w     = (const float*)d_in[4];
    const float* targ_aff   = (const float*)d_in[5];
    float* out = (float*)d_out;
    unsigned int* pmin = (unsigned int*)d_ws;            // rows [0,64K) + cols [64K,128K)
    float* partials = (float*)(pmin + 2 * BB * NN);      // 32 floats

    // init mins to a huge positive float (0x7f7f7f7f = 3.39e38)
    hipMemsetAsync(pmin, 0x7f, (size_t)2 * BB * NN * sizeof(unsigned int), stream);

    chamfer_kernel<<<dim3(BB * NRTILE * NCTILE), TPB, 0, stream>>>(
        pred_shape, targ_shape, targ_aff, pmin);
    reduce_pmin<<<32, TPB, 0, stream>>>(pmin, partials);
    final_combine<<<1, TPB, 0, stream>>>(partials, pred_w, targ_w,
                                         pred_aff, targ_aff, out);
}